// Round 2
// baseline (1629.038 us; speedup 1.0000x reference)
//
#include <hip/hip_runtime.h>
#include <hip/hip_bf16.h>
#include <cstdint>
#include <cstddef>

typedef __bf16 bf16x8 __attribute__((ext_vector_type(8)));
typedef __bf16 bf16x4 __attribute__((ext_vector_type(4)));
typedef float  f32x4  __attribute__((ext_vector_type(4)));

union BF8 { bf16x8 v; __bf16 e[8]; };
union BF4 { bf16x4 v; __bf16 e[4]; };

#define S_LEN 2048
#define D_DIM 128
#define QBLK  64
#define KBLK  64
#define NSTEP (S_LEN / KBLK)

#define KS_OFF 0          // K tile: [64][128] bf16, row stride 256B, XOR-swizzled
#define VT_OFF 16384      // V^T tile: [128][64] bf16, row stride 128B, XOR-swizzled
#define P_OFF  32768      // P tiles: 4 waves x [16][64] bf16 (2KB each), swizzled
#define SMEM_BYTES 40960

__device__ __forceinline__ unsigned tf_rotl(unsigned x, int r) {
  return (x << r) | (x >> (32 - r));
}

// JAX threefry2x32 with key (0,42) (jax.random.key(42)), partitionable path:
// x0 = counts_hi = 0, x1 = counts_lo = ctr; 32-bit bits = out0 ^ out1.
__device__ __forceinline__ unsigned tf_bits(unsigned ctr) {
  const unsigned ks1 = 42u, ks2 = 0x1BD11BF0u;  // 0 ^ 42 ^ 0x1BD11BDA
  unsigned x0 = 0u;            // + ks0 (=0)
  unsigned x1 = ctr + ks1;
#define TFR(r) { x0 += x1; x1 = tf_rotl(x1, r); x1 ^= x0; }
  TFR(13) TFR(15) TFR(26) TFR(6)
  x0 += ks1; x1 += ks2 + 1u;
  TFR(17) TFR(29) TFR(16) TFR(24)
  x0 += ks2; x1 += 2u;         // ks0 + 2
  TFR(13) TFR(15) TFR(26) TFR(6)
  x1 += ks1 + 3u;              // x0 += ks0 (=0)
  TFR(17) TFR(29) TFR(16) TFR(24)
  x0 += ks1; x1 += ks2 + 4u;
  TFR(13) TFR(15) TFR(26) TFR(6)
  x0 += ks2; x1 += 5u;         // ks0 + 5
#undef TFR
  return x0 ^ x1;
}

__global__ __launch_bounds__(256) void attn_dropout_kernel(
    const float* __restrict__ Q, const float* __restrict__ K,
    const float* __restrict__ V, float* __restrict__ O) {
  __shared__ unsigned char smem[SMEM_BYTES] __attribute__((aligned(16)));

  const int tid  = threadIdx.x;
  const int lane = tid & 63;
  const int wid  = tid >> 6;
  const int lm   = lane & 15;   // MFMA "column"/row-of-16 index
  const int lq   = lane >> 4;   // quarter

  // XCD-aware swizzle: 2048 wgs, 8 XCDs; give each XCD 8 contiguous bh's.
  const unsigned wg  = blockIdx.x;
  const unsigned xcd = wg & 7u;
  const unsigned j   = wg >> 3;          // 0..255
  const unsigned bh  = xcd * 8u + (j >> 5);  // 0..63
  const unsigned qt  = j & 31u;          // q-tile 0..31

  const size_t base = (size_t)bh * S_LEN * D_DIM;
  const float* Qb = Q + base;
  const float* Kb = K + base;
  const float* Vb = V + base;
  float*       Ob = O + base;

  const int q0 = (int)qt * QBLK + wid * 16;

  // ---- load Q fragments (16 rows x 128, bf16), A-layout: [lm][8*lq + j]
  BF8 qf[4];
  {
    const float* qg = Qb + (size_t)(q0 + lm) * D_DIM + lq * 8;
#pragma unroll
    for (int kc = 0; kc < 4; ++kc) {
      const float4 a = *(const float4*)(qg + kc * 32);
      const float4 b = *(const float4*)(qg + kc * 32 + 4);
      qf[kc].e[0] = (__bf16)a.x; qf[kc].e[1] = (__bf16)a.y;
      qf[kc].e[2] = (__bf16)a.z; qf[kc].e[3] = (__bf16)a.w;
      qf[kc].e[4] = (__bf16)b.x; qf[kc].e[5] = (__bf16)b.y;
      qf[kc].e[6] = (__bf16)b.z; qf[kc].e[7] = (__bf16)b.w;
    }
  }

  f32x4 acc[8];
#pragma unroll
  for (int i = 0; i < 8; ++i) { acc[i][0]=0.f; acc[i][1]=0.f; acc[i][2]=0.f; acc[i][3]=0.f; }
  float mrun[4] = {-INFINITY, -INFINITY, -INFINITY, -INFINITY};
  float lrun[4] = {0.f, 0.f, 0.f, 0.f};

  const float scale = 0.08838834764831843f;  // 128^-0.5

  const int srow = tid >> 2;          // staging row 0..63
  const int sc0  = (tid & 3) << 5;    // staging col0: 0/32/64/96
  const unsigned ssw = (unsigned)((srow & 7) << 4);

  for (int kt = 0; kt < NSTEP; ++kt) {
    const int kbase = kt * KBLK;
    __syncthreads();  // previous tile fully consumed
    // ---- stage K (row-major, swizzled) and V (transposed, swizzled), f32->bf16
    {
      const float* kg = Kb + (size_t)(kbase + srow) * D_DIM + sc0;
      const float* vg = Vb + (size_t)(kbase + srow) * D_DIM + sc0;
#pragma unroll
      for (int i = 0; i < 8; ++i) {
        const float4 kq = *(const float4*)(kg + i * 4);
        BF4 kb;
        kb.e[0] = (__bf16)kq.x; kb.e[1] = (__bf16)kq.y;
        kb.e[2] = (__bf16)kq.z; kb.e[3] = (__bf16)kq.w;
        *(bf16x4*)(&smem[KS_OFF + srow * 256 +
                         (((unsigned)((sc0 + i * 4) * 2)) ^ ssw)]) = kb.v;
        const float4 vq = *(const float4*)(vg + i * 4);
        const float vv[4] = {vq.x, vq.y, vq.z, vq.w};
#pragma unroll
        for (int jj = 0; jj < 4; ++jj) {
          const int d = sc0 + i * 4 + jj;
          *(__bf16*)(&smem[VT_OFF + d * 128 +
                           (((unsigned)(srow * 2)) ^ (unsigned)((d & 7) << 4))]) =
              (__bf16)vv[jj];
        }
      }
    }
    __syncthreads();

    // ---- S = Q K^T (16 x 64 per wave)
    f32x4 s[4];
#pragma unroll
    for (int nt = 0; nt < 4; ++nt) { s[nt][0]=0.f; s[nt][1]=0.f; s[nt][2]=0.f; s[nt][3]=0.f; }
#pragma unroll
    for (int nt = 0; nt < 4; ++nt) {
      const int krow = nt * 16 + lm;
      const unsigned rsw = (unsigned)((krow & 7) << 4);
#pragma unroll
      for (int kc = 0; kc < 4; ++kc) {
        const bf16x8 kf = *(const bf16x8*)(&smem[KS_OFF + krow * 256 +
                             (((unsigned)(kc * 64 + lq * 16)) ^ rsw)]);
        s[nt] = __builtin_amdgcn_mfma_f32_16x16x32_bf16(qf[kc].v, kf, s[nt], 0, 0, 0);
      }
    }
#pragma unroll
    for (int nt = 0; nt < 4; ++nt) {
      s[nt][0] *= scale; s[nt][1] *= scale; s[nt][2] *= scale; s[nt][3] *= scale;
    }

    // ---- online softmax (rows live in (lq, r); reduce across 16 lanes lm)
    float alpha[4];
#pragma unroll
    for (int r = 0; r < 4; ++r) {
      float v = fmaxf(fmaxf(s[0][r], s[1][r]), fmaxf(s[2][r], s[3][r]));
      v = fmaxf(v, __shfl_xor(v, 1));
      v = fmaxf(v, __shfl_xor(v, 2));
      v = fmaxf(v, __shfl_xor(v, 4));
      v = fmaxf(v, __shfl_xor(v, 8));
      const float mn = fmaxf(mrun[r], v);
      alpha[r] = __expf(mrun[r] - mn);
      mrun[r] = mn;
    }

    float rowsum[4] = {0.f, 0.f, 0.f, 0.f};
    const unsigned f_base = (bh << 22);
#pragma unroll
    for (int nt = 0; nt < 4; ++nt) {
      const unsigned kcol = (unsigned)(kbase + nt * 16 + lm);
#pragma unroll
      for (int r = 0; r < 4; ++r) {
        const float p = __expf(s[nt][r] - mrun[r]);
        rowsum[r] += p;  // denominator uses PRE-dropout p
        const unsigned qrow = (unsigned)(q0 + lq * 4 + r);
        const unsigned bits = tf_bits(f_base | (qrow << 11) | kcol);
        const float pd = ((bits >> 9) < 7549747u) ? p : 0.f;  // keep <=> u < 0.9f
        const int prow = lq * 4 + r;
        const int pcol = nt * 16 + lm;
        *(__bf16*)(&smem[P_OFF + wid * 2048 + prow * 128 +
                         (((unsigned)(pcol * 2)) ^ (unsigned)((prow & 7) << 4))]) =
            (__bf16)pd;
      }
    }
#pragma unroll
    for (int r = 0; r < 4; ++r) {
      float v = rowsum[r];
      v += __shfl_xor(v, 1);
      v += __shfl_xor(v, 2);
      v += __shfl_xor(v, 4);
      v += __shfl_xor(v, 8);
      lrun[r] = lrun[r] * alpha[r] + v;
    }
#pragma unroll
    for (int nt = 0; nt < 8; ++nt) {
#pragma unroll
      for (int r = 0; r < 4; ++r) acc[nt][r] *= alpha[r];
    }

    __asm__ volatile("s_waitcnt lgkmcnt(0)" ::: "memory");  // P writes visible (wave-private)

    // ---- O += P V  (A = P 16x64, B = V 64x128 via V^T tile)
    BF8 pa[2];
    {
      const unsigned psw = (unsigned)((lm & 7) << 4);
      pa[0].v = *(const bf16x8*)(&smem[P_OFF + wid * 2048 + lm * 128 +
                                      (((unsigned)(lq * 16)) ^ psw)]);
      pa[1].v = *(const bf16x8*)(&smem[P_OFF + wid * 2048 + lm * 128 +
                                      (((unsigned)(64 + lq * 16)) ^ psw)]);
    }
#pragma unroll
    for (int nt = 0; nt < 8; ++nt) {
      const int d = nt * 16 + lm;
      const unsigned vsw = (unsigned)((d & 7) << 4);
#pragma unroll
      for (int kc = 0; kc < 2; ++kc) {
        const bf16x8 vf = *(const bf16x8*)(&smem[VT_OFF + d * 128 +
                               (((unsigned)(kc * 64 + lq * 16)) ^ vsw)]);
        acc[nt] = __builtin_amdgcn_mfma_f32_16x16x32_bf16(pa[kc].v, vf, acc[nt], 0, 0, 0);
      }
    }
  }

  // ---- epilogue: O = acc / (0.9 * l)
  float inv[4];
#pragma unroll
  for (int r = 0; r < 4; ++r) inv[r] = 1.0f / (0.9f * lrun[r]);
#pragma unroll
  for (int nt = 0; nt < 8; ++nt) {
#pragma unroll
    for (int r = 0; r < 4; ++r) {
      Ob[(size_t)(q0 + lq * 4 + r) * D_DIM + nt * 16 + lm] = acc[nt][r] * inv[r];
    }
  }
}

extern "C" void kernel_launch(void* const* d_in, const int* in_sizes, int n_in,
                              void* d_out, int out_size, void* d_ws, size_t ws_size,
                              hipStream_t stream) {
  const float* Q = (const float*)d_in[0];
  const float* K = (const float*)d_in[1];
  const float* V = (const float*)d_in[2];
  float* O = (float*)d_out;
  dim3 grid(64 * 32);   // 64 (b,h) pairs x 32 q-tiles of 64 rows
  dim3 block(256);      // 4 waves
  hipLaunchKernelGGL(attn_dropout_kernel, grid, block, 0, stream, Q, K, V, O);
}

// Round 5
// 860.524 us; speedup vs baseline: 1.8931x; 1.8931x over previous
//
#include <hip/hip_runtime.h>
#include <hip/hip_bf16.h>
#include <cstdint>
#include <cstddef>

typedef __bf16 bf16x8 __attribute__((ext_vector_type(8)));
typedef __bf16 bf16x4 __attribute__((ext_vector_type(4)));
typedef float  f32x4  __attribute__((ext_vector_type(4)));

union BF8 { bf16x8 v; __bf16 e[8]; };
union BF4 { bf16x4 v; __bf16 e[4]; };

#define S_LEN 2048
#define D_DIM 128
#define QBLK  64
#define KBLK  64
#define NSTEP (S_LEN / KBLK)

__device__ __forceinline__ unsigned tf_rotl(unsigned x, int r) {
  return (x << r) | (x >> (32 - r));
}

// JAX threefry2x32, key(42) -> (0,42), partitionable path: bits = o0^o1, ctr in lo.
// Verified bit-exact in round 2 (absmax 3.9e-3 = bf16 rounding only).
__device__ __forceinline__ unsigned tf_bits(unsigned ctr) {
  const unsigned ks1 = 42u, ks2 = 0x1BD11BF0u;
  unsigned x0 = 0u;
  unsigned x1 = ctr + ks1;
#define TFR(r) { x0 += x1; x1 = tf_rotl(x1, r); x1 ^= x0; }
  TFR(13) TFR(15) TFR(26) TFR(6)
  x0 += ks1; x1 += ks2 + 1u;
  TFR(17) TFR(29) TFR(16) TFR(24)
  x0 += ks2; x1 += 2u;
  TFR(13) TFR(15) TFR(26) TFR(6)
  x1 += ks1 + 3u;
  TFR(17) TFR(29) TFR(16) TFR(24)
  x0 += ks1; x1 += ks2 + 4u;
  TFR(13) TFR(15) TFR(26) TFR(6)
  x0 += ks2; x1 += 5u;
#undef TFR
  return x0 ^ x1;
}

// ---------------- prep A: K f32 -> bf16 (row-major, same layout) ----------------
__global__ __launch_bounds__(256) void prep_convert_k(const float* __restrict__ K,
                                                      __bf16* __restrict__ Kb) {
  const size_t g = ((size_t)blockIdx.x * 256 + threadIdx.x) * 8;
  const float4 a = *(const float4*)(K + g);
  const float4 b = *(const float4*)(K + g + 4);
  BF8 o;
  o.e[0] = (__bf16)a.x; o.e[1] = (__bf16)a.y; o.e[2] = (__bf16)a.z; o.e[3] = (__bf16)a.w;
  o.e[4] = (__bf16)b.x; o.e[5] = (__bf16)b.y; o.e[6] = (__bf16)b.z; o.e[7] = (__bf16)b.w;
  *(bf16x8*)(Kb + g) = o.v;
}

// ---------------- prep B: V f32 [bh][k][d] -> Vt bf16 [bh][d][k] ----------------
__global__ __launch_bounds__(256) void prep_transpose_v(const float* __restrict__ V,
                                                        __bf16* __restrict__ Vt) {
  __shared__ float tile[64 * 128];  // float4-chunk swizzled: chunk c' = c ^ (r&31)
  const int tid = threadIdx.x;
  const unsigned bh = blockIdx.x >> 5;
  const int kb = (int)(blockIdx.x & 31u) * 64;
  const float* Vb = V + (size_t)bh * S_LEN * D_DIM;
  __bf16* Vtb = Vt + (size_t)bh * S_LEN * D_DIM;

  {
    const int r = tid >> 2;
    const int q4 = tid & 3;
    const float* src = Vb + (size_t)(kb + r) * D_DIM + q4 * 32;
#pragma unroll
    for (int i = 0; i < 8; ++i) {
      const int c = q4 * 8 + i;
      *(float4*)(&tile[r * 128 + ((c ^ (r & 31)) << 2)]) = *(const float4*)(src + i * 4);
    }
  }
  __syncthreads();
  {
    const int d = tid >> 1;
    const int sub = tid & 1;
#pragma unroll
    for (int s = 0; s < 4; ++s) {
      BF8 o;
#pragma unroll
      for (int j = 0; j < 8; ++j) {
        const int r = s * 16 + sub * 8 + j;
        const float x = tile[r * 128 + (((d >> 2) ^ (r & 31)) << 2) + (d & 3)];
        o.e[j] = (__bf16)x;
      }
      *(bf16x8*)(Vtb + (size_t)d * S_LEN + kb + sub * 8 + s * 16) = o.v;
    }
  }
}

// ---------------- main fused attention ----------------
// LDS layout:
//   K tile  [64][128] bf16 = 16 KB, double-buffered: KOFF0=0, KOFF1=16384
//   V^T tile[128][64] bf16 = 16 KB:                  VOFF = 32768
//   P tiles 4 x [16][64] bf16 = 8 KB:                POFF = 49152
#define KOFF0 0u
#define KOFF1 16384u
#define VOFF  32768u
#define POFF  49152u
#define SMEM_FAST 57344

__device__ __forceinline__ void gl16(const __bf16* g, unsigned char* smem, unsigned lds_off) {
  __builtin_amdgcn_global_load_lds(
      (const __attribute__((address_space(1))) unsigned int*)g,
      (__attribute__((address_space(3))) unsigned int*)(smem + lds_off), 16, 0, 0);
}

__global__ __launch_bounds__(256) void attn_fast(
    const float* __restrict__ Q, const __bf16* __restrict__ Kbf,
    const __bf16* __restrict__ Vt, float* __restrict__ O) {
  __shared__ unsigned char smem[SMEM_FAST] __attribute__((aligned(16)));

  const int tid  = threadIdx.x;
  const int lane = tid & 63;
  const int wid  = tid >> 6;
  const int lm   = lane & 15;
  const int lq   = lane >> 4;

  const unsigned wg  = blockIdx.x;
  const unsigned xcd = wg & 7u;
  const unsigned j   = wg >> 3;
  const unsigned bh  = xcd * 8u + (j >> 5);
  const unsigned qt  = j & 31u;

  const float* Qb = Q + (size_t)bh * S_LEN * D_DIM;
  float*       Ob = O + (size_t)bh * S_LEN * D_DIM;
  const __bf16* Kb = Kbf + (size_t)bh * S_LEN * D_DIM;
  const __bf16* Vb = Vt  + (size_t)bh * S_LEN * D_DIM;

  const int q0 = (int)qt * QBLK + wid * 16;

  // Q fragments (A-layout): qf[kc].e[j] = Q[q0+lm][kc*32 + lq*8 + j]
  BF8 qf[4];
  {
    const float* qg = Qb + (size_t)(q0 + lm) * D_DIM + lq * 8;
#pragma unroll
    for (int kc = 0; kc < 4; ++kc) {
      const float4 a = *(const float4*)(qg + kc * 32);
      const float4 b = *(const float4*)(qg + kc * 32 + 4);
      qf[kc].e[0] = (__bf16)a.x; qf[kc].e[1] = (__bf16)a.y;
      qf[kc].e[2] = (__bf16)a.z; qf[kc].e[3] = (__bf16)a.w;
      qf[kc].e[4] = (__bf16)b.x; qf[kc].e[5] = (__bf16)b.y;
      qf[kc].e[6] = (__bf16)b.z; qf[kc].e[7] = (__bf16)b.w;
    }
  }

  // staging: linear LDS dest (HW adds lane*16), inverse-XOR pre-swizzled global src.
  unsigned kldso[4], vldso[4];
  size_t kgo[4], vgo[4];
#pragma unroll
  for (int i = 0; i < 4; ++i) {
    const int krl = wid * 16 + i * 4 + (lane >> 4);
    const unsigned kcb = ((unsigned)(lane & 15) * 16u) ^ ((unsigned)(krl & 7) << 4);
    kgo[i] = (size_t)krl * D_DIM + kcb / 2;
    kldso[i] = (unsigned)(wid * 4096 + i * 1024);
    const int vdr = wid * 32 + i * 8 + (lane >> 3);
    const unsigned vcb = ((unsigned)(lane & 7) * 16u) ^ ((unsigned)(vdr & 7) << 4);
    vgo[i] = (size_t)vdr * S_LEN + vcb / 2;
    vldso[i] = VOFF + (unsigned)(wid * 4096 + i * 1024);
  }

  f32x4 acc[8];
#pragma unroll
  for (int i = 0; i < 8; ++i) { acc[i][0]=0.f; acc[i][1]=0.f; acc[i][2]=0.f; acc[i][3]=0.f; }
  float mrun[4] = {-INFINITY, -INFINITY, -INFINITY, -INFINITY};
  float lrun[4] = {0.f, 0.f, 0.f, 0.f};
  const float scale = 0.08838834764831843f;  // 128^-0.5

  // prologue: stage K(0) -> buf0, V(0) -> VOFF
#pragma unroll
  for (int i = 0; i < 4; ++i) gl16(Kb + kgo[i], smem, KOFF0 + kldso[i]);
#pragma unroll
  for (int i = 0; i < 4; ++i) gl16(Vb + vgo[i], smem, vldso[i]);
  __asm__ volatile("s_waitcnt vmcnt(0)" ::: "memory");
  __builtin_amdgcn_s_barrier();
  __builtin_amdgcn_sched_barrier(0);

  for (int kt = 0; kt < NSTEP; ++kt) {
    const int kbase = kt * KBLK;
    const unsigned kcur = (kt & 1) ? KOFF1 : KOFF0;
    const unsigned knxt = (kt & 1) ? KOFF0 : KOFF1;
    const int kb_next = ((kt + 1) & (NSTEP - 1)) * KBLK;  // wrap keeps vmcnt uniform

    // issue K(t+1) into the other buffer
#pragma unroll
    for (int i = 0; i < 4; ++i) gl16(Kb + (size_t)kb_next * D_DIM + kgo[i], smem, knxt + kldso[i]);

    // K(t) ready: outstanding = K(t)(4 oldest) + V(t)(4) + K(t+1)(4);
    // vmcnt(8) drains exactly K(t) (vmcnt retires in issue order).
    __asm__ volatile("s_waitcnt vmcnt(8)" ::: "memory");
    __builtin_amdgcn_s_barrier();
    __builtin_amdgcn_sched_barrier(0);

    // ---- S = Q K^T
    f32x4 s[4];
#pragma unroll
    for (int nt = 0; nt < 4; ++nt) { s[nt][0]=0.f; s[nt][1]=0.f; s[nt][2]=0.f; s[nt][3]=0.f; }
#pragma unroll
    for (int nt = 0; nt < 4; ++nt) {
      const int krow = nt * 16 + lm;
      const unsigned rsw = (unsigned)((krow & 7) << 4);
#pragma unroll
      for (int kc = 0; kc < 4; ++kc) {
        const bf16x8 kf = *(const bf16x8*)(&smem[kcur + krow * 256 +
                             (((unsigned)(kc * 64 + lq * 16)) ^ rsw)]);
        s[nt] = __builtin_amdgcn_mfma_f32_16x16x32_bf16(qf[kc].v, kf, s[nt], 0, 0, 0);
      }
    }
#pragma unroll
    for (int nt = 0; nt < 4; ++nt) {
      s[nt][0] *= scale; s[nt][1] *= scale; s[nt][2] *= scale; s[nt][3] *= scale;
    }

    // ---- online softmax
    float alpha[4];
#pragma unroll
    for (int r = 0; r < 4; ++r) {
      float v = fmaxf(fmaxf(s[0][r], s[1][r]), fmaxf(s[2][r], s[3][r]));
      v = fmaxf(v, __shfl_xor(v, 1));
      v = fmaxf(v, __shfl_xor(v, 2));
      v = fmaxf(v, __shfl_xor(v, 4));
      v = fmaxf(v, __shfl_xor(v, 8));
      const float mn = fmaxf(mrun[r], v);
      alpha[r] = __expf(mrun[r] - mn);
      mrun[r] = mn;
    }

    float rowsum[4] = {0.f, 0.f, 0.f, 0.f};
    const unsigned f_base = (bh << 22);
#pragma unroll
    for (int nt = 0; nt < 4; ++nt) {
      const unsigned kcol = (unsigned)(kbase + nt * 16 + lm);
#pragma unroll
      for (int r = 0; r < 4; ++r) {
        const float p = __expf(s[nt][r] - mrun[r]);
        rowsum[r] += p;  // denominator uses PRE-dropout p
        const unsigned qrow = (unsigned)(q0 + lq * 4 + r);
        const unsigned bits = tf_bits(f_base | (qrow << 11) | kcol);
        const float pd = ((bits >> 9) < 7549747u) ? p : 0.f;  // keep <=> u < 0.9f
        const int prow = lq * 4 + r;
        const int pcol = nt * 16 + lm;
        *(__bf16*)(&smem[POFF + wid * 2048 + prow * 128 +
                         (((unsigned)(pcol * 2)) ^ (unsigned)((prow & 7) << 4))]) =
            (__bf16)pd;
      }
    }
#pragma unroll
    for (int r = 0; r < 4; ++r) {
      float v = rowsum[r];
      v += __shfl_xor(v, 1);
      v += __shfl_xor(v, 2);
      v += __shfl_xor(v, 4);
      v += __shfl_xor(v, 8);
      lrun[r] = lrun[r] * alpha[r] + v;
    }
#pragma unroll
    for (int nt = 0; nt < 8; ++nt) {
#pragma unroll
      for (int r = 0; r < 4; ++r) acc[nt][r] *= alpha[r];
    }

    __asm__ volatile("s_waitcnt lgkmcnt(0)" ::: "memory");  // P visible (wave-private)
    __builtin_amdgcn_sched_barrier(0);

    BF8 pa[2];
    {
      const unsigned psw = (unsigned)((lm & 7) << 4);
      pa[0].v = *(const bf16x8*)(&smem[POFF + wid * 2048 + lm * 128 +
                                      (((unsigned)(lq * 16)) ^ psw)]);
      pa[1].v = *(const bf16x8*)(&smem[POFF + wid * 2048 + lm * 128 +
                                      (((unsigned)(64 + lq * 16)) ^ psw)]);
    }

    // V(t) ready: outstanding = V(t)(4 oldest) + K(t+1)(4); vmcnt(4) drains V(t).
    __asm__ volatile("s_waitcnt vmcnt(4)" ::: "memory");
    __builtin_amdgcn_s_barrier();
    __builtin_amdgcn_sched_barrier(0);

    // ---- O += P V (B-fragments from V^T tile)
#pragma unroll
    for (int nt = 0; nt < 8; ++nt) {
      const int d = nt * 16 + lm;
      const unsigned vsw = (unsigned)((d & 7) << 4);
#pragma unroll
      for (int kc = 0; kc < 2; ++kc) {
        const bf16x8 vf = *(const bf16x8*)(&smem[VOFF + d * 128 +
                               (((unsigned)(kc * 64 + lq * 16)) ^ vsw)]);
        acc[nt] = __builtin_amdgcn_mfma_f32_16x16x32_bf16(pa[kc].v, vf, acc[nt], 0, 0, 0);
      }
    }

    __asm__ volatile("" ::: "memory");   // pin V reads before the barrier
    __builtin_amdgcn_s_barrier();        // all waves done reading VOFF
    __builtin_amdgcn_sched_barrier(0);
    // issue V(t+1) (lands during next tile's QK^T + softmax)
#pragma unroll
    for (int i = 0; i < 4; ++i) gl16(Vb + kb_next + vgo[i], smem, vldso[i]);
  }

  // FIX (round 4 -> 5): drain ALL outstanding LDS-DMAs before the workgroup can
  // retire. Without this, the 8 wrap-issued K(0)/V(0) DMAs from iter 31 are
  // still in flight at s_endpgm; the LDS slot is reassigned to a successor
  // workgroup and the late writes corrupt ITS tiles (intermittent, dispatch-
  // timing dependent -- exactly the graph-replay-only failure seen in round 4).
  __asm__ volatile("s_waitcnt vmcnt(0) lgkmcnt(0)" ::: "memory");
  __builtin_amdgcn_sched_barrier(0);

  float inv[4];
#pragma unroll
  for (int r = 0; r < 4; ++r) inv[r] = 1.0f / (0.9f * lrun[r]);
#pragma unroll
  for (int nt = 0; nt < 8; ++nt) {
#pragma unroll
    for (int r = 0; r < 4; ++r) {
      Ob[(size_t)(q0 + lq * 4 + r) * D_DIM + nt * 16 + lm] = acc[nt][r] * inv[r];
    }
  }
}

// ---------------- fallback (round-2 kernel, proven correct @1590us) ----------------
#define KS_OFF 0
#define VT_OFF 16384
#define P_OFF  32768
#define SMEM_BYTES 40960

__global__ __launch_bounds__(256) void attn_dropout_kernel(
    const float* __restrict__ Q, const float* __restrict__ K,
    const float* __restrict__ V, float* __restrict__ O) {
  __shared__ unsigned char smem[SMEM_BYTES] __attribute__((aligned(16)));
  const int tid  = threadIdx.x;
  const int lane = tid & 63;
  const int wid  = tid >> 6;
  const int lm   = lane & 15;
  const int lq   = lane >> 4;
  const unsigned wg  = blockIdx.x;
  const unsigned xcd = wg & 7u;
  const unsigned j   = wg >> 3;
  const unsigned bh  = xcd * 8u + (j >> 5);
  const unsigned qt  = j & 31u;
  const size_t base = (size_t)bh * S_LEN * D_DIM;
  const float* Qb = Q + base;
  const float* Kb = K + base;
  const float* Vb = V + base;
  float*       Ob = O + base;
  const int q0 = (int)qt * QBLK + wid * 16;
  BF8 qf[4];
  {
    const float* qg = Qb + (size_t)(q0 + lm) * D_DIM + lq * 8;
#pragma unroll
    for (int kc = 0; kc < 4; ++kc) {
      const float4 a = *(const float4*)(qg + kc * 32);
      const float4 b = *(const float4*)(qg + kc * 32 + 4);
      qf[kc].e[0] = (__bf16)a.x; qf[kc].e[1] = (__bf16)a.y;
      qf[kc].e[2] = (__bf16)a.z; qf[kc].e[3] = (__bf16)a.w;
      qf[kc].e[4] = (__bf16)b.x; qf[kc].e[5] = (__bf16)b.y;
      qf[kc].e[6] = (__bf16)b.z; qf[kc].e[7] = (__bf16)b.w;
    }
  }
  f32x4 acc[8];
#pragma unroll
  for (int i = 0; i < 8; ++i) { acc[i][0]=0.f; acc[i][1]=0.f; acc[i][2]=0.f; acc[i][3]=0.f; }
  float mrun[4] = {-INFINITY, -INFINITY, -INFINITY, -INFINITY};
  float lrun[4] = {0.f, 0.f, 0.f, 0.f};
  const float scale = 0.08838834764831843f;
  const int srow = tid >> 2;
  const int sc0  = (tid & 3) << 5;
  const unsigned ssw = (unsigned)((srow & 7) << 4);
  for (int kt = 0; kt < NSTEP; ++kt) {
    const int kbase = kt * KBLK;
    __syncthreads();
    {
      const float* kg = Kb + (size_t)(kbase + srow) * D_DIM + sc0;
      const float* vg = Vb + (size_t)(kbase + srow) * D_DIM + sc0;
#pragma unroll
      for (int i = 0; i < 8; ++i) {
        const float4 kq = *(const float4*)(kg + i * 4);
        BF4 kb;
        kb.e[0] = (__bf16)kq.x; kb.e[1] = (__bf16)kq.y;
        kb.e[2] = (__bf16)kq.z; kb.e[3] = (__bf16)kq.w;
        *(bf16x4*)(&smem[KS_OFF + srow * 256 +
                         (((unsigned)((sc0 + i * 4) * 2)) ^ ssw)]) = kb.v;
        const float4 vq = *(const float4*)(vg + i * 4);
        const float vv[4] = {vq.x, vq.y, vq.z, vq.w};
#pragma unroll
        for (int jj = 0; jj < 4; ++jj) {
          const int d = sc0 + i * 4 + jj;
          *(__bf16*)(&smem[VT_OFF + d * 128 +
                           (((unsigned)(srow * 2)) ^ (unsigned)((d & 7) << 4))]) =
              (__bf16)vv[jj];
        }
      }
    }
    __syncthreads();
    f32x4 s[4];
#pragma unroll
    for (int nt = 0; nt < 4; ++nt) { s[nt][0]=0.f; s[nt][1]=0.f; s[nt][2]=0.f; s[nt][3]=0.f; }
#pragma unroll
    for (int nt = 0; nt < 4; ++nt) {
      const int krow = nt * 16 + lm;
      const unsigned rsw = (unsigned)((krow & 7) << 4);
#pragma unroll
      for (int kc = 0; kc < 4; ++kc) {
        const bf16x8 kf = *(const bf16x8*)(&smem[KS_OFF + krow * 256 +
                             (((unsigned)(kc * 64 + lq * 16)) ^ rsw)]);
        s[nt] = __builtin_amdgcn_mfma_f32_16x16x32_bf16(qf[kc].v, kf, s[nt], 0, 0, 0);
      }
    }
#pragma unroll
    for (int nt = 0; nt < 4; ++nt) {
      s[nt][0] *= scale; s[nt][1] *= scale; s[nt][2] *= scale; s[nt][3] *= scale;
    }
    float alpha[4];
#pragma unroll
    for (int r = 0; r < 4; ++r) {
      float v = fmaxf(fmaxf(s[0][r], s[1][r]), fmaxf(s[2][r], s[3][r]));
      v = fmaxf(v, __shfl_xor(v, 1));
      v = fmaxf(v, __shfl_xor(v, 2));
      v = fmaxf(v, __shfl_xor(v, 4));
      v = fmaxf(v, __shfl_xor(v, 8));
      const float mn = fmaxf(mrun[r], v);
      alpha[r] = __expf(mrun[r] - mn);
      mrun[r] = mn;
    }
    float rowsum[4] = {0.f, 0.f, 0.f, 0.f};
    const unsigned f_base = (bh << 22);
#pragma unroll
    for (int nt = 0; nt < 4; ++nt) {
      const unsigned kcol = (unsigned)(kbase + nt * 16 + lm);
#pragma unroll
      for (int r = 0; r < 4; ++r) {
        const float p = __expf(s[nt][r] - mrun[r]);
        rowsum[r] += p;
        const unsigned qrow = (unsigned)(q0 + lq * 4 + r);
        const unsigned bits = tf_bits(f_base | (qrow << 11) | kcol);
        const float pd = ((bits >> 9) < 7549747u) ? p : 0.f;
        const int prow = lq * 4 + r;
        const int pcol = nt * 16 + lm;
        *(__bf16*)(&smem[P_OFF + wid * 2048 + prow * 128 +
                         (((unsigned)(pcol * 2)) ^ (unsigned)((prow & 7) << 4))]) =
            (__bf16)pd;
      }
    }
#pragma unroll
    for (int r = 0; r < 4; ++r) {
      float v = rowsum[r];
      v += __shfl_xor(v, 1);
      v += __shfl_xor(v, 2);
      v += __shfl_xor(v, 4);
      v += __shfl_xor(v, 8);
      lrun[r] = lrun[r] * alpha[r] + v;
    }
#pragma unroll
    for (int nt = 0; nt < 8; ++nt) {
#pragma unroll
      for (int r = 0; r < 4; ++r) acc[nt][r] *= alpha[r];
    }
    __asm__ volatile("s_waitcnt lgkmcnt(0)" ::: "memory");
    BF8 pa[2];
    {
      const unsigned psw = (unsigned)((lm & 7) << 4);
      pa[0].v = *(const bf16x8*)(&smem[P_OFF + wid * 2048 + lm * 128 +
                                      (((unsigned)(lq * 16)) ^ psw)]);
      pa[1].v = *(const bf16x8*)(&smem[P_OFF + wid * 2048 + lm * 128 +
                                      (((unsigned)(64 + lq * 16)) ^ psw)]);
    }
#pragma unroll
    for (int nt = 0; nt < 8; ++nt) {
      const int d = nt * 16 + lm;
      const unsigned vsw = (unsigned)((d & 7) << 4);
#pragma unroll
      for (int kc = 0; kc < 2; ++kc) {
        const bf16x8 vf = *(const bf16x8*)(&smem[VT_OFF + d * 128 +
                               (((unsigned)(kc * 64 + lq * 16)) ^ vsw)]);
        acc[nt] = __builtin_amdgcn_mfma_f32_16x16x32_bf16(pa[kc].v, vf, acc[nt], 0, 0, 0);
      }
    }
  }
  float inv[4];
#pragma unroll
  for (int r = 0; r < 4; ++r) inv[r] = 1.0f / (0.9f * lrun[r]);
#pragma unroll
  for (int nt = 0; nt < 8; ++nt) {
#pragma unroll
    for (int r = 0; r < 4; ++r) {
      Ob[(size_t)(q0 + lq * 4 + r) * D_DIM + nt * 16 + lm] = acc[nt][r] * inv[r];
    }
  }
}

extern "C" void kernel_launch(void* const* d_in, const int* in_sizes, int n_in,
                              void* d_out, int out_size, void* d_ws, size_t ws_size,
                              hipStream_t stream) {
  const float* Q = (const float*)d_in[0];
  const float* K = (const float*)d_in[1];
  const float* V = (const float*)d_in[2];
  float* O = (float*)d_out;
  const size_t total = (size_t)64 * S_LEN * D_DIM;          // 16,777,216 elems
  const size_t ws_need = 2 * total * sizeof(__bf16);        // 134,217,728 B

  if (ws_size >= ws_need) {
    __bf16* Kb = (__bf16*)d_ws;
    __bf16* Vt = Kb + total;
    hipLaunchKernelGGL(prep_convert_k, dim3((unsigned)(total / (256 * 8))), dim3(256), 0, stream, K, Kb);
    hipLaunchKernelGGL(prep_transpose_v, dim3(2048), dim3(256), 0, stream, V, Vt);
    hipLaunchKernelGGL(attn_fast, dim3(2048), dim3(256), 0, stream, Q, Kb, Vt, O);
  } else {
    hipLaunchKernelGGL(attn_dropout_kernel, dim3(2048), dim3(256), 0, stream, Q, K, V, O);
  }
}